// Round 2
// baseline (257.497 us; speedup 1.0000x reference)
//
#include <hip/hip_runtime.h>
#include <hip/hip_bf16.h>

namespace {

constexpr int B = 8, C = 64, H = 256, W = 256;
constexpr int HW = H * W;

__global__ __launch_bounds__(256) void warp_kernel(
    const float* __restrict__ phi,
    const float* __restrict__ xenc,
    const float* __restrict__ mm,
    float* __restrict__ out)
{
    const int tid = blockIdx.x * 256 + threadIdx.x;  // one thread = one pixel
    const int w = tid & (W - 1);
    const int h = (tid >> 8) & (H - 1);
    const int b = tid >> 16;
    const int hw = h * W + w;

    // per-pixel scalars (coalesced 4B loads: lane == w)
    const float p0 = phi[(size_t)(b * 2 + 0) * HW + hw];
    const float p1 = phi[(size_t)(b * 2 + 1) * HW + hw];
    const float mv = mm[(size_t)b * HW + hw];

    // normalized grid exactly as reference
    const float gx = (2.0f * ((float)w + p0)) / (float)(W - 1) - 1.0f + 2.0f * p0;
    const float gy = (2.0f * ((float)h + p1)) / (float)(H - 1) - 1.0f + 2.0f * p1;

    // grid_sample align_corners=False unnormalization
    const float ix = (gx + 1.0f) * (0.5f * (float)W) - 0.5f;
    const float iy = (gy + 1.0f) * (0.5f * (float)H) - 0.5f;

    const float x0f = floorf(ix);
    const float y0f = floorf(iy);
    const float fx1 = ix - x0f, fx0 = 1.0f - fx1;
    const float fy1 = iy - y0f, fy0 = 1.0f - fy1;

    // clamp in float first (safe int conversion), indices like ref's clip
    const float wm1 = (float)(W - 1), hm1 = (float)(H - 1);
    const int x0 = (int)fminf(fmaxf(x0f,        0.0f), wm1);
    const int x1 = (int)fminf(fmaxf(x0f + 1.0f, 0.0f), wm1);
    const int y0 = (int)fminf(fmaxf(y0f,        0.0f), hm1);
    const int y1 = (int)fminf(fmaxf(y0f + 1.0f, 0.0f), hm1);

    const bool vx0 = (x0f >= 0.0f) && (x0f < (float)W);
    const bool vx1 = (x0f + 1.0f >= 0.0f) && (x0f + 1.0f < (float)W);
    const bool vy0 = (y0f >= 0.0f) && (y0f < (float)H);
    const bool vy1 = (y0f + 1.0f >= 0.0f) && (y0f + 1.0f < (float)H);

    // fold validity AND the mask m into the 4 weights (all weights >= 0)
    const float w00 = fy0 * fx0 * ((vy0 && vx0) ? mv : 0.0f);
    const float w01 = fy0 * fx1 * ((vy0 && vx1) ? mv : 0.0f);
    const float w10 = fy1 * fx0 * ((vy1 && vx0) ? mv : 0.0f);
    const float w11 = fy1 * fx1 * ((vy1 && vx1) ? mv : 0.0f);

    // all weights are non-negative and finite; sum==0 <=> all contributions zero
    const bool doGather = (w00 + w01 + w10 + w11) != 0.0f;

    const int o00 = y0 * W + x0;
    const int o01 = y0 * W + x1;
    const int o10 = y1 * W + x0;
    const int o11 = y1 * W + x1;

    const float* __restrict__ xb = xenc + (size_t)b * C * HW;
    float* __restrict__ ob = out + (size_t)b * C * HW + hw;

    #pragma unroll 4
    for (int c = 0; c < C; ++c) {
        float v = 0.0f;
        if (doGather) {  // exec-masked: fully-OOB lanes issue no gathers
            const float* __restrict__ xc = xb + (size_t)c * HW;
            v = xc[o00] * w00
              + xc[o01] * w01
              + xc[o10] * w10
              + xc[o11] * w11;
        }
        ob[(size_t)c * HW] = v;  // coalesced 256B/wave store
    }
}

}  // namespace

extern "C" void kernel_launch(void* const* d_in, const int* in_sizes, int n_in,
                              void* d_out, int out_size, void* d_ws, size_t ws_size,
                              hipStream_t stream) {
    const float* phi  = (const float*)d_in[0];
    const float* xenc = (const float*)d_in[1];
    const float* mm   = (const float*)d_in[2];
    float* out = (float*)d_out;

    const int pixels = B * H * W;  // 524288
    warp_kernel<<<dim3(pixels / 256), dim3(256), 0, stream>>>(phi, xenc, mm, out);
}

// Round 3
// 244.737 us; speedup vs baseline: 1.0521x; 1.0521x over previous
//
#include <hip/hip_runtime.h>

namespace {

constexpr int B = 8, C = 64, H = 256, W = 256;
constexpr int HW = H * W;
constexpr int TP = 64;        // pixels per block (one w-tile of a row)
constexpr int TSTRIDE = 68;   // LDS tile row stride in floats (pad for b128 reads)

typedef float v4f __attribute__((ext_vector_type(4)));

__global__ __launch_bounds__(256) void warp_kernel(
    const float* __restrict__ phi,
    const float* __restrict__ xenc,
    const float* __restrict__ mm,
    float* __restrict__ out)
{
    __shared__ float tile[64 * TSTRIDE];  // [c][p], zero-filled
    __shared__ float s_w[4][TP];          // compacted weights (m folded in)
    __shared__ int   s_o[4][TP];          // compacted corner offsets (h*W+w)
    __shared__ int   s_p[TP];             // compacted pixel index in tile
    __shared__ int   s_n;                 // number of in-bounds pixels

    const int t   = threadIdx.x;
    const int bid = blockIdx.x;           // B*H*(W/64) = 8192 blocks
    const int wt  = bid & 3;
    const int h   = (bid >> 2) & (H - 1);
    const int b   = bid >> 10;
    const int w0  = wt * 64;

    // ---- zero the tile (all 256 threads, float4 writes) ----
    {
        v4f z = {0.f, 0.f, 0.f, 0.f};
        for (int i = t; i < (64 * TSTRIDE) / 4; i += 256)
            *(v4f*)&tile[i * 4] = z;
    }

    // ---- stage 1: wave 0 computes per-pixel params + ballot-compacts ----
    if (t < 64) {
        const int lane = t;
        const int w    = w0 + lane;
        const int hw   = h * W + w;

        const float p0 = phi[(size_t)(b * 2 + 0) * HW + hw];
        const float p1 = phi[(size_t)(b * 2 + 1) * HW + hw];
        const float mv = mm[(size_t)b * HW + hw];

        const float gx = (2.0f * ((float)w + p0)) / (float)(W - 1) - 1.0f + 2.0f * p0;
        const float gy = (2.0f * ((float)h + p1)) / (float)(H - 1) - 1.0f + 2.0f * p1;
        const float ix = (gx + 1.0f) * (0.5f * (float)W) - 0.5f;
        const float iy = (gy + 1.0f) * (0.5f * (float)H) - 0.5f;

        const float x0f = floorf(ix);
        const float y0f = floorf(iy);
        const float fx1 = ix - x0f, fx0 = 1.0f - fx1;
        const float fy1 = iy - y0f, fy0 = 1.0f - fy1;

        const float wm1 = (float)(W - 1), hm1 = (float)(H - 1);
        const int x0 = (int)fminf(fmaxf(x0f,        0.0f), wm1);
        const int x1 = (int)fminf(fmaxf(x0f + 1.0f, 0.0f), wm1);
        const int y0 = (int)fminf(fmaxf(y0f,        0.0f), hm1);
        const int y1 = (int)fminf(fmaxf(y0f + 1.0f, 0.0f), hm1);

        const bool vx0 = (x0f >= 0.0f) && (x0f < (float)W);
        const bool vx1 = (x0f + 1.0f >= 0.0f) && (x0f + 1.0f < (float)W);
        const bool vy0 = (y0f >= 0.0f) && (y0f < (float)H);
        const bool vy1 = (y0f + 1.0f >= 0.0f) && (y0f + 1.0f < (float)H);

        const float w00 = fy0 * fx0 * ((vy0 && vx0) ? mv : 0.0f);
        const float w01 = fy0 * fx1 * ((vy0 && vx1) ? mv : 0.0f);
        const float w10 = fy1 * fx0 * ((vy1 && vx0) ? mv : 0.0f);
        const float w11 = fy1 * fx1 * ((vy1 && vx1) ? mv : 0.0f);

        const bool inb = (w00 + w01 + w10 + w11) != 0.0f;

        const unsigned long long mask = __ballot(inb);
        const int pos = __popcll(mask & ((1ULL << lane) - 1ULL));
        if (inb) {
            s_w[0][pos] = w00;  s_w[1][pos] = w01;
            s_w[2][pos] = w10;  s_w[3][pos] = w11;
            s_o[0][pos] = y0 * W + x0;
            s_o[1][pos] = y0 * W + x1;
            s_o[2][pos] = y1 * W + x0;
            s_o[3][pos] = y1 * W + x1;
            s_p[pos]    = lane;
        }
        if (lane == 0) s_n = __popcll(mask);
    }
    __syncthreads();

    // ---- stage 2: dense gathers, one wave per in-bounds pixel ----
    {
        const int wv   = t >> 6;     // wave id 0..3
        const int lane = t & 63;     // channel
        const int n    = s_n;
        const float* __restrict__ xb = xenc + ((size_t)b * C + lane) * HW;
        for (int i = wv; i < n; i += 4) {
            const float w00 = s_w[0][i], w01 = s_w[1][i];
            const float w10 = s_w[2][i], w11 = s_w[3][i];
            const int o00 = s_o[0][i], o01 = s_o[1][i];
            const int o10 = s_o[2][i], o11 = s_o[3][i];
            const int p   = s_p[i];
            const float v = xb[o00] * w00 + xb[o01] * w01
                          + xb[o10] * w10 + xb[o11] * w11;
            tile[lane * TSTRIDE + p] = v;
        }
    }
    __syncthreads();

    // ---- stage 3: transposed store, nontemporal float4 ----
    {
        const size_t obase = (size_t)b * C * HW + (size_t)h * W + w0;
        const int cl = t >> 4;            // 0..15
        const int p4 = (t & 15) * 4;      // 0..60
        #pragma unroll
        for (int pass = 0; pass < 4; ++pass) {
            const int c = pass * 16 + cl;
            v4f v = *(const v4f*)&tile[c * TSTRIDE + p4];
            __builtin_nontemporal_store(v, (v4f*)(out + obase + (size_t)c * HW + p4));
        }
    }
}

}  // namespace

extern "C" void kernel_launch(void* const* d_in, const int* in_sizes, int n_in,
                              void* d_out, int out_size, void* d_ws, size_t ws_size,
                              hipStream_t stream) {
    const float* phi  = (const float*)d_in[0];
    const float* xenc = (const float*)d_in[1];
    const float* mm   = (const float*)d_in[2];
    float* out = (float*)d_out;

    const int blocks = B * H * (W / 64);  // 8192
    warp_kernel<<<dim3(blocks), dim3(256), 0, stream>>>(phi, xenc, mm, out);
}